// Round 4
// baseline (15830.196 us; speedup 1.0000x reference)
//
#include <hip/hip_runtime.h>

// CNF fused RK4, 3-chain bf16 MFMA (primal + 2 JVP tangents), W2-only in LDS.
// kt-outer / acc-resident loop: N in halves (96 acc VGPRs), layer-1 A-frags
// recomputed per half so only 12 A-frag VGPRs are live at a time. No spills.
// R4 fix: injective layer-1 pad-swizzle k + (k>>3)  (R3's was non-injective).

typedef __attribute__((ext_vector_type(8))) short bf16x8;
typedef __attribute__((ext_vector_type(8))) unsigned short u16x8;
typedef __attribute__((ext_vector_type(4))) float f32x4;

__device__ __forceinline__ unsigned short f2bf(float f) {
  unsigned u = __builtin_bit_cast(unsigned, f);
  u += 0x7FFFu + ((u >> 16) & 1u);   // RNE
  return (unsigned short)(u >> 16);
}

__device__ __forceinline__ float fast_tanh(float z) {
  float e = __expf(2.0f * z);
  return 1.0f - 2.0f * __builtin_amdgcn_rcpf(e + 1.0f);
}

// ---------- prep: swizzle W2 -> bf16 B-fragment layout in d_ws ----------
// chunk c holds B[k=(c>>4)*32+(l>>4)*8+bb][j=(c&15)*16+(l&15)] at c*512+l*8+bb
__global__ void cnf_prep(const float* __restrict__ W2,
                         unsigned short* __restrict__ w2s) {
  int t = blockIdx.x * blockDim.x + threadIdx.x;   // 8192 threads
  if (t >= 8192) return;
  int c = t >> 6, l = t & 63;
  int kbase = ((c >> 4) << 5) + ((l >> 4) << 3);
  int j = ((c & 15) << 4) + (l & 15);
  int o = t * 8;
  #pragma unroll
  for (int bb = 0; bb < 8; ++bb)
    w2s[o + bb] = f2bf(W2[(kbase + bb) * 256 + j]);
}

// ---------- main fused RK4 kernel ----------
__launch_bounds__(512, 2)
__global__ void cnf_rk4_v4(const float* __restrict__ xg,
                           const float* __restrict__ W1,
                           const float* __restrict__ b1,
                           const float* __restrict__ W2f,
                           const float* __restrict__ b2,
                           const float* __restrict__ W3,
                           const float* __restrict__ b3,
                           const unsigned short* __restrict__ w2s,
                           const int* __restrict__ nsp,
                           float* __restrict__ out,
                           int Btot, int useWs) {
  __shared__ __align__(16) unsigned short w2u[65536];  // 128 KB, B-frag layout
  __shared__ float4 l1c[288];   // (W1_0,W1_1,W1_2,b1), stored at k + (k>>3)
  __shared__ float4 eps[256];   // (W3_0, W3_1, b2, 0)
  __shared__ float  b3s[2];
  __shared__ float  cxs[128][2];
  __shared__ float  sxs[128][2];
  __shared__ float  ksum[128][2];
  __shared__ float  lsum[128];
  __shared__ float  lds_ld[128];

  const int tid  = threadIdx.x;
  const int lane = tid & 63;
  const int wv   = tid >> 6;
  const int ln15 = lane & 15;
  const int g    = lane >> 4;

  if (useWs) {            // fast staging: vector copy of pre-swizzled bf16
    u16x8* dst = (u16x8*)w2u;
    const u16x8* src = (const u16x8*)w2s;
    for (int i = tid; i < 8192; i += 512) dst[i] = src[i];
  } else {                // fallback: convert in-kernel
    for (int i = tid; i < 65536; i += 512) {
      int c = i >> 9, l = (i >> 3) & 63, bb = i & 7;
      int k = ((c >> 4) << 5) + ((l >> 4) << 3) + bb;
      int j = ((c & 15) << 4) + (l & 15);
      w2u[i] = f2bf(W2f[k * 256 + j]);
    }
  }
  for (int i = tid; i < 256; i += 512) {
    l1c[i + (i >> 3)] = make_float4(W1[i], W1[256 + i], W1[512 + i], b1[i]);
    eps[i] = make_float4(W3[2 * i], W3[2 * i + 1], b2[i], 0.0f);
  }
  if (tid == 0) { b3s[0] = b3[0]; b3s[1] = b3[1]; }

  const int base = blockIdx.x * 128;
  for (int i = tid; i < 128; i += 512) {
    if (base + i < Btot) {
      float2 v = ((const float2*)xg)[base + i];
      cxs[i][0] = v.x; cxs[i][1] = v.y;
      sxs[i][0] = v.x; sxs[i][1] = v.y;
    } else {
      cxs[i][0] = 0.f; cxs[i][1] = 0.f; sxs[i][0] = 0.f; sxs[i][1] = 0.f;
    }
    lds_ld[i] = 0.0f;
  }
  __syncthreads();

  int nst = nsp[0];
  if (nst < 1 || nst > 100000) {
    float fv = __builtin_bit_cast(float, nsp[0]);
    nst = (int)fv;
  }
  if (nst < 1) nst = 1;
  if (nst > 1000) nst = 1000;
  const int nsteps = nst - 1;
  const float hstep = (nsteps > 0) ? 1.0f / (float)nsteps : 0.0f;

  const bf16x8* w2v = (const bf16x8*)w2u;
  const int sA = wv * 16 + ln15;

  for (int step = 0; step < nsteps; ++step) {
    const float t0 = step * hstep;
    #pragma unroll 1
    for (int st = 0; st < 4; ++st) {
      const float tcur = t0 + ((st == 1 || st == 2) ? 0.5f * hstep
                                                    : (st == 3 ? hstep : 0.0f));
      const float x0 = sxs[sA][0];
      const float x1 = sxs[sA][1];
      float po0[4] = {0,0,0,0}, po1[4] = {0,0,0,0}, ptr_[4] = {0,0,0,0};

      #pragma unroll 1
      for (int nh = 0; nh < 2; ++nh) {           // N half: j in [nh*128, +128)
        f32x4 aP[8], aU0[8], aU1[8];
        #pragma unroll
        for (int ni = 0; ni < 8; ++ni) {
          aP[ni] = (f32x4)0.0f; aU0[ni] = (f32x4)0.0f; aU1[ni] = (f32x4)0.0f;
        }
        #pragma unroll
        for (int kt = 0; kt < 8; ++kt) {
          // layer-1 A-frags for this kt only (12 VGPRs live)
          bf16x8 hf, u0f, u1f;
          const int kb = kt * 32 + g * 8 + (kt * 4 + g);  // k + (k>>3) swizzle
          #pragma unroll
          for (int bb = 0; bb < 8; ++bb) {
            float4 q = l1c[kb + bb];
            float z = fmaf(x0, q.x, fmaf(x1, q.y, fmaf(tcur, q.z, q.w)));
            float h = fast_tanh(z);
            float th = 1.0f - h * h;
            hf[bb]  = (short)f2bf(h);
            u0f[bb] = (short)f2bf(th * q.x);
            u1f[bb] = (short)f2bf(th * q.y);
          }
          #pragma unroll
          for (int ni = 0; ni < 8; ++ni) {
            bf16x8 bw = w2v[(kt * 16 + nh * 8 + ni) * 64 + lane];  // 1 read, 3 MFMAs
            aP[ni]  = __builtin_amdgcn_mfma_f32_16x16x32_bf16(hf,  bw, aP[ni],  0, 0, 0);
            aU0[ni] = __builtin_amdgcn_mfma_f32_16x16x32_bf16(u0f, bw, aU0[ni], 0, 0, 0);
            aU1[ni] = __builtin_amdgcn_mfma_f32_16x16x32_bf16(u1f, bw, aU1[ni], 0, 0, 0);
          }
        }
        // epilogue for this half; C layout: col=lane&15 (j), row idx b (sample)
        #pragma unroll
        for (int ni = 0; ni < 8; ++ni) {
          const int j = (nh * 8 + ni) * 16 + ln15;
          const float4 e = eps[j];               // w30, w31, b2
          #pragma unroll
          for (int b = 0; b < 4; ++b) {
            float z2 = aP[ni][b] + e.z;
            float h2 = fast_tanh(z2);
            float th2 = 1.0f - h2 * h2;
            po0[b]  = fmaf(h2, e.x, po0[b]);
            po1[b]  = fmaf(h2, e.y, po1[b]);
            ptr_[b] = fmaf(th2, fmaf(aU0[ni][b], e.x, aU1[ni][b] * e.y), ptr_[b]);
          }
        }
      }

      // reduce over 16 j-lanes, RK4 state update
      #pragma unroll
      for (int b = 0; b < 4; ++b) {
        float r0 = po0[b], r1 = po1[b], r2 = ptr_[b];
        #pragma unroll
        for (int off = 8; off > 0; off >>= 1) {
          r0 += __shfl_xor(r0, off, 64);
          r1 += __shfl_xor(r1, off, 64);
          r2 += __shfl_xor(r2, off, 64);
        }
        if (ln15 == 0) {
          const int s = wv * 16 + g * 4 + b;
          const float dx0 = r0 + b3s[0];
          const float dx1 = r1 + b3s[1];
          const float trv = r2;
          float k0, k1v, kl;
          if (st == 0) { k0 = dx0; k1v = dx1; kl = trv; }
          else {
            const float w = (st == 3) ? 1.0f : 2.0f;
            k0 = ksum[s][0] + w * dx0; k1v = ksum[s][1] + w * dx1; kl = lsum[s] + w * trv;
          }
          ksum[s][0] = k0; ksum[s][1] = k1v; lsum[s] = kl;
          if (st < 3) {
            const float a = (st == 2) ? hstep : 0.5f * hstep;
            sxs[s][0] = cxs[s][0] + a * dx0;
            sxs[s][1] = cxs[s][1] + a * dx1;
          } else {
            const float c6 = hstep * (1.0f / 6.0f);
            const float nx0 = cxs[s][0] + c6 * k0;
            const float nx1 = cxs[s][1] + c6 * k1v;
            cxs[s][0] = nx0; cxs[s][1] = nx1;
            sxs[s][0] = nx0; sxs[s][1] = nx1;
            lds_ld[s] -= 0.01f * c6 * kl;        // -TRACE_SCALE * (h/6) * sum
          }
        }
      }
    }
  }
  __syncthreads();

  for (int i = tid; i < 128; i += 512) {
    const int gs = base + i;
    if (gs < Btot) {
      ((float2*)out)[gs] = make_float2(cxs[i][0], cxs[i][1]);
      out[2 * Btot + gs] = lds_ld[i];
    }
  }
}

extern "C" void kernel_launch(void* const* d_in, const int* in_sizes, int n_in,
                              void* d_out, int out_size, void* d_ws, size_t ws_size,
                              hipStream_t stream) {
  const float* x  = (const float*)d_in[0];
  const float* W1 = (const float*)d_in[1];
  const float* b1 = (const float*)d_in[2];
  const float* W2 = (const float*)d_in[3];
  const float* b2 = (const float*)d_in[4];
  const float* W3 = (const float*)d_in[5];
  const float* b3 = (const float*)d_in[6];
  const int* nsp  = (const int*)d_in[7];
  float* out = (float*)d_out;

  const int Btot = in_sizes[0] / 2;
  const int nblocks = (Btot + 127) / 128;

  const int useWs = (ws_size >= 65536u * sizeof(unsigned short)) ? 1 : 0;
  unsigned short* w2s = (unsigned short*)d_ws;
  if (useWs)
    cnf_prep<<<dim3(32), dim3(256), 0, stream>>>(W2, w2s);
  cnf_rk4_v4<<<dim3(nblocks), dim3(512), 0, stream>>>(
      x, W1, b1, W2, b2, W3, b3, w2s, nsp, out, Btot, useWs);
}

// Round 5
// 6887.782 us; speedup vs baseline: 2.2983x; 2.2983x over previous
//
#include <hip/hip_runtime.h>

// CNF fused RK4, 3-chain bf16 MFMA, W2-only in LDS.
// R5: N-quarters (48 acc VGPRs) so the whole stage fits the compiler's
// 128 arch-VGPR budget -> no scratch spills. bf16 packing via
// v_cvt_pk_bf16_f32 (register-only inline asm).

typedef __attribute__((ext_vector_type(8))) short bf16x8;
typedef __attribute__((ext_vector_type(8))) unsigned short u16x8;
typedef __attribute__((ext_vector_type(4))) float f32x4;
typedef __attribute__((ext_vector_type(4))) unsigned u32x4;

__device__ __forceinline__ unsigned short f2bf(float f) {
  unsigned u = __builtin_bit_cast(unsigned, f);
  u += 0x7FFFu + ((u >> 16) & 1u);   // RNE
  return (unsigned short)(u >> 16);
}

__device__ __forceinline__ unsigned pk2bf(float lo, float hi) {
  unsigned r;
  asm("v_cvt_pk_bf16_f32 %0, %1, %2" : "=v"(r) : "v"(lo), "v"(hi));
  return r;
}

__device__ __forceinline__ float fast_tanh(float z) {
  float e = __expf(2.0f * z);
  return 1.0f - 2.0f * __builtin_amdgcn_rcpf(e + 1.0f);
}

// ---------- prep: swizzle W2 -> bf16 B-fragment layout in d_ws ----------
// chunk c holds B[k=(c>>4)*32+(l>>4)*8+bb][j=(c&15)*16+(l&15)] at c*512+l*8+bb
__global__ void cnf_prep(const float* __restrict__ W2,
                         unsigned short* __restrict__ w2s) {
  int t = blockIdx.x * blockDim.x + threadIdx.x;   // 8192 threads
  if (t >= 8192) return;
  int c = t >> 6, l = t & 63;
  int kbase = ((c >> 4) << 5) + ((l >> 4) << 3);
  int j = ((c & 15) << 4) + (l & 15);
  int o = t * 8;
  #pragma unroll
  for (int bb = 0; bb < 8; ++bb)
    w2s[o + bb] = f2bf(W2[(kbase + bb) * 256 + j]);
}

// ---------- main fused RK4 kernel ----------
__launch_bounds__(512, 2)
__global__ void cnf_rk4_v5(const float* __restrict__ xg,
                           const float* __restrict__ W1,
                           const float* __restrict__ b1,
                           const float* __restrict__ W2f,
                           const float* __restrict__ b2,
                           const float* __restrict__ W3,
                           const float* __restrict__ b3,
                           const unsigned short* __restrict__ w2s,
                           const int* __restrict__ nsp,
                           float* __restrict__ out,
                           int Btot, int useWs) {
  __shared__ __align__(16) unsigned short w2u[65536];  // 128 KB, B-frag layout
  __shared__ float4 l1c[288];   // (W1_0,W1_1,W1_2,b1) at k + (k>>3) (injective)
  __shared__ float4 eps[256];   // (W3_0, W3_1, b2, 0)
  __shared__ float  b3s[2];
  __shared__ float  cxs[128][2];
  __shared__ float  sxs[128][2];
  __shared__ float  ksum[128][2];
  __shared__ float  lsum[128];
  __shared__ float  lds_ld[128];

  const int tid  = threadIdx.x;
  const int lane = tid & 63;
  const int wv   = tid >> 6;
  const int ln15 = lane & 15;
  const int g    = lane >> 4;

  if (useWs) {            // fast staging: vector copy of pre-swizzled bf16
    u16x8* dst = (u16x8*)w2u;
    const u16x8* src = (const u16x8*)w2s;
    for (int i = tid; i < 8192; i += 512) dst[i] = src[i];
  } else {                // fallback: convert in-kernel
    for (int i = tid; i < 65536; i += 512) {
      int c = i >> 9, l = (i >> 3) & 63, bb = i & 7;
      int k = ((c >> 4) << 5) + ((l >> 4) << 3) + bb;
      int j = ((c & 15) << 4) + (l & 15);
      w2u[i] = f2bf(W2f[k * 256 + j]);
    }
  }
  for (int i = tid; i < 256; i += 512) {
    l1c[i + (i >> 3)] = make_float4(W1[i], W1[256 + i], W1[512 + i], b1[i]);
    eps[i] = make_float4(W3[2 * i], W3[2 * i + 1], b2[i], 0.0f);
  }
  if (tid == 0) { b3s[0] = b3[0]; b3s[1] = b3[1]; }

  const int base = blockIdx.x * 128;
  for (int i = tid; i < 128; i += 512) {
    if (base + i < Btot) {
      float2 v = ((const float2*)xg)[base + i];
      cxs[i][0] = v.x; cxs[i][1] = v.y;
      sxs[i][0] = v.x; sxs[i][1] = v.y;
    } else {
      cxs[i][0] = 0.f; cxs[i][1] = 0.f; sxs[i][0] = 0.f; sxs[i][1] = 0.f;
    }
    lds_ld[i] = 0.0f;
  }
  __syncthreads();

  int nst = nsp[0];
  if (nst < 1 || nst > 100000) {
    float fv = __builtin_bit_cast(float, nsp[0]);
    nst = (int)fv;
  }
  if (nst < 1) nst = 1;
  if (nst > 1000) nst = 1000;
  const int nsteps = nst - 1;
  const float hstep = (nsteps > 0) ? 1.0f / (float)nsteps : 0.0f;

  const bf16x8* w2v = (const bf16x8*)w2u;
  const int sA = wv * 16 + ln15;

  for (int step = 0; step < nsteps; ++step) {
    const float t0 = step * hstep;
    #pragma unroll 1
    for (int st = 0; st < 4; ++st) {
      const float tcur = t0 + ((st == 1 || st == 2) ? 0.5f * hstep
                                                    : (st == 3 ? hstep : 0.0f));
      const float x0 = sxs[sA][0];
      const float x1 = sxs[sA][1];
      float po0[4] = {0,0,0,0}, po1[4] = {0,0,0,0}, ptr_[4] = {0,0,0,0};

      #pragma unroll 1
      for (int qn = 0; qn < 4; ++qn) {           // N quarter: j in [qn*64, +64)
        f32x4 aP[4], aU0[4], aU1[4];
        #pragma unroll
        for (int ni = 0; ni < 4; ++ni) {
          aP[ni] = (f32x4)0.0f; aU0[ni] = (f32x4)0.0f; aU1[ni] = (f32x4)0.0f;
        }
        #pragma unroll
        for (int kt = 0; kt < 8; ++kt) {
          // layer-1 A-frags for this kt (pair-wise, cvt_pk packing)
          const int kb = kt * 32 + g * 8 + (kt * 4 + g);  // k + (k>>3) swizzle
          u32x4 hu, u0u, u1u;
          #pragma unroll
          for (int pp = 0; pp < 4; ++pp) {
            float4 qa = l1c[kb + 2 * pp];
            float4 qb = l1c[kb + 2 * pp + 1];
            float za = fmaf(x0, qa.x, fmaf(x1, qa.y, fmaf(tcur, qa.z, qa.w)));
            float zb = fmaf(x0, qb.x, fmaf(x1, qb.y, fmaf(tcur, qb.z, qb.w)));
            float ha = fast_tanh(za);
            float hb = fast_tanh(zb);
            float ta = 1.0f - ha * ha;
            float tb = 1.0f - hb * hb;
            hu[pp]  = pk2bf(ha, hb);
            u0u[pp] = pk2bf(ta * qa.x, tb * qb.x);
            u1u[pp] = pk2bf(ta * qa.y, tb * qb.y);
          }
          bf16x8 hf  = __builtin_bit_cast(bf16x8, hu);
          bf16x8 u0f = __builtin_bit_cast(bf16x8, u0u);
          bf16x8 u1f = __builtin_bit_cast(bf16x8, u1u);
          #pragma unroll
          for (int ni = 0; ni < 4; ++ni) {
            bf16x8 bw = w2v[(kt * 16 + qn * 4 + ni) * 64 + lane]; // 1 read, 3 MFMAs
            aP[ni]  = __builtin_amdgcn_mfma_f32_16x16x32_bf16(hf,  bw, aP[ni],  0, 0, 0);
            aU0[ni] = __builtin_amdgcn_mfma_f32_16x16x32_bf16(u0f, bw, aU0[ni], 0, 0, 0);
            aU1[ni] = __builtin_amdgcn_mfma_f32_16x16x32_bf16(u1f, bw, aU1[ni], 0, 0, 0);
          }
        }
        // epilogue for this quarter; C layout: col=lane&15 (j), row b (sample)
        #pragma unroll
        for (int ni = 0; ni < 4; ++ni) {
          const int j = (qn * 4 + ni) * 16 + ln15;
          const float4 e = eps[j];               // w30, w31, b2
          #pragma unroll
          for (int b = 0; b < 4; ++b) {
            float z2 = aP[ni][b] + e.z;
            float h2 = fast_tanh(z2);
            float th2 = 1.0f - h2 * h2;
            po0[b]  = fmaf(h2, e.x, po0[b]);
            po1[b]  = fmaf(h2, e.y, po1[b]);
            ptr_[b] = fmaf(th2, fmaf(aU0[ni][b], e.x, aU1[ni][b] * e.y), ptr_[b]);
          }
        }
      }

      // reduce over 16 j-lanes, RK4 state update
      #pragma unroll
      for (int b = 0; b < 4; ++b) {
        float r0 = po0[b], r1 = po1[b], r2 = ptr_[b];
        #pragma unroll
        for (int off = 8; off > 0; off >>= 1) {
          r0 += __shfl_xor(r0, off, 64);
          r1 += __shfl_xor(r1, off, 64);
          r2 += __shfl_xor(r2, off, 64);
        }
        if (ln15 == 0) {
          const int s = wv * 16 + g * 4 + b;
          const float dx0 = r0 + b3s[0];
          const float dx1 = r1 + b3s[1];
          const float trv = r2;
          float k0, k1v, kl;
          if (st == 0) { k0 = dx0; k1v = dx1; kl = trv; }
          else {
            const float w = (st == 3) ? 1.0f : 2.0f;
            k0 = ksum[s][0] + w * dx0; k1v = ksum[s][1] + w * dx1; kl = lsum[s] + w * trv;
          }
          ksum[s][0] = k0; ksum[s][1] = k1v; lsum[s] = kl;
          if (st < 3) {
            const float a = (st == 2) ? hstep : 0.5f * hstep;
            sxs[s][0] = cxs[s][0] + a * dx0;
            sxs[s][1] = cxs[s][1] + a * dx1;
          } else {
            const float c6 = hstep * (1.0f / 6.0f);
            const float nx0 = cxs[s][0] + c6 * k0;
            const float nx1 = cxs[s][1] + c6 * k1v;
            cxs[s][0] = nx0; cxs[s][1] = nx1;
            sxs[s][0] = nx0; sxs[s][1] = nx1;
            lds_ld[s] -= 0.01f * c6 * kl;        // -TRACE_SCALE * (h/6) * sum
          }
        }
      }
    }
  }
  __syncthreads();

  for (int i = tid; i < 128; i += 512) {
    const int gs = base + i;
    if (gs < Btot) {
      ((float2*)out)[gs] = make_float2(cxs[i][0], cxs[i][1]);
      out[2 * Btot + gs] = lds_ld[i];
    }
  }
}

extern "C" void kernel_launch(void* const* d_in, const int* in_sizes, int n_in,
                              void* d_out, int out_size, void* d_ws, size_t ws_size,
                              hipStream_t stream) {
  const float* x  = (const float*)d_in[0];
  const float* W1 = (const float*)d_in[1];
  const float* b1 = (const float*)d_in[2];
  const float* W2 = (const float*)d_in[3];
  const float* b2 = (const float*)d_in[4];
  const float* W3 = (const float*)d_in[5];
  const float* b3 = (const float*)d_in[6];
  const int* nsp  = (const int*)d_in[7];
  float* out = (float*)d_out;

  const int Btot = in_sizes[0] / 2;
  const int nblocks = (Btot + 127) / 128;

  const int useWs = (ws_size >= 65536u * sizeof(unsigned short)) ? 1 : 0;
  unsigned short* w2s = (unsigned short*)d_ws;
  if (useWs)
    cnf_prep<<<dim3(32), dim3(256), 0, stream>>>(W2, w2s);
  cnf_rk4_v5<<<dim3(nblocks), dim3(512), 0, stream>>>(
      x, W1, b1, W2, b2, W3, b3, w2s, nsp, out, Btot, useWs);
}

// Round 6
// 4835.407 us; speedup vs baseline: 3.2738x; 1.4244x over previous
//
#include <hip/hip_runtime.h>

// CNF fused RK4, 2-chain bf16 MFMA:
//   primal: h1 x W2   (W2 bf16 B-frags in LDS, 128 KB)
//   trace:  th1 x Btr (Btr[k,j]=W2[k,j]*(W1[0,k]W3[j,0]+W1[1,k]W3[j,1]),
//                      bf16 B-frags in global d_ws, L1/L2-resident)
// Layer-1 A-frags computed ONCE per stage (hoisted across the 4 N-quarters):
// 64 VGPRs of A-frags + 32 acc fits the 128-reg budget (R4/R5 evidence).

typedef __attribute__((ext_vector_type(8))) short bf16x8;
typedef __attribute__((ext_vector_type(8))) unsigned short u16x8;
typedef __attribute__((ext_vector_type(4))) float f32x4;
typedef __attribute__((ext_vector_type(4))) unsigned u32x4;

__device__ __forceinline__ unsigned short f2bf(float f) {
  unsigned u = __builtin_bit_cast(unsigned, f);
  u += 0x7FFFu + ((u >> 16) & 1u);   // RNE
  return (unsigned short)(u >> 16);
}

__device__ __forceinline__ unsigned pk2bf(float lo, float hi) {
  unsigned r;
  asm("v_cvt_pk_bf16_f32 %0, %1, %2" : "=v"(r) : "v"(lo), "v"(hi));
  return r;
}

__device__ __forceinline__ float fast_tanh(float z) {
  float e;
  float zs = z * 2.8853900817779268f;    // 2*log2(e)
  asm("v_exp_f32 %0, %1" : "=v"(e) : "v"(zs));   // e = exp(2z)
  return 1.0f - 2.0f * __builtin_amdgcn_rcpf(e + 1.0f);
}

// ---------- prep: swizzled bf16 W2 and Btr B-fragment tables ----------
// chunk c holds B[k=(c>>4)*32+(l>>4)*8+bb][j=(c&15)*16+(l&15)] at c*512+l*8+bb
__global__ void cnf_prep(const float* __restrict__ W1,
                         const float* __restrict__ W2,
                         const float* __restrict__ W3,
                         unsigned short* __restrict__ w2s,
                         unsigned short* __restrict__ btrs) {
  int t = blockIdx.x * blockDim.x + threadIdx.x;   // 8192 threads
  if (t >= 8192) return;
  int c = t >> 6, l = t & 63;
  int kbase = ((c >> 4) << 5) + ((l >> 4) << 3);
  int j = ((c & 15) << 4) + (l & 15);
  float w30 = W3[2 * j], w31 = W3[2 * j + 1];
  int o = t * 8;
  #pragma unroll
  for (int bb = 0; bb < 8; ++bb) {
    int k = kbase + bb;
    float w2 = W2[k * 256 + j];
    w2s[o + bb] = f2bf(w2);
    btrs[o + bb] = f2bf(w2 * (W1[k] * w30 + W1[256 + k] * w31));
  }
}

// ---------- main fused RK4 kernel (2-chain, hoisted L1) ----------
__launch_bounds__(512, 2)
__global__ void cnf_rk4_v6(const float* __restrict__ xg,
                           const float* __restrict__ W1,
                           const float* __restrict__ b1,
                           const float* __restrict__ b2,
                           const float* __restrict__ W3,
                           const float* __restrict__ b3,
                           const unsigned short* __restrict__ w2s,
                           const unsigned short* __restrict__ btrs,
                           const int* __restrict__ nsp,
                           float* __restrict__ out,
                           int Btot) {
  __shared__ __align__(16) unsigned short w2u[65536];  // 128 KB, B-frag layout
  __shared__ float4 l1c[288];   // (W1_0,W1_1,W1_2,b1) at k + (k>>3) (injective)
  __shared__ float4 eps[256];   // (W3_0, W3_1, b2, 0)
  __shared__ float  b3s[2];
  __shared__ float  cxs[128][2];
  __shared__ float  sxs[128][2];
  __shared__ float  ksum[128][2];
  __shared__ float  lsum[128];
  __shared__ float  lds_ld[128];

  const int tid  = threadIdx.x;
  const int lane = tid & 63;
  const int wv   = tid >> 6;
  const int ln15 = lane & 15;
  const int g    = lane >> 4;

  {  // stage pre-swizzled W2 into LDS (vector copy, L2/L3-hot)
    u16x8* dst = (u16x8*)w2u;
    const u16x8* src = (const u16x8*)w2s;
    for (int i = tid; i < 8192; i += 512) dst[i] = src[i];
  }
  for (int i = tid; i < 256; i += 512) {
    l1c[i + (i >> 3)] = make_float4(W1[i], W1[256 + i], W1[512 + i], b1[i]);
    eps[i] = make_float4(W3[2 * i], W3[2 * i + 1], b2[i], 0.0f);
  }
  if (tid == 0) { b3s[0] = b3[0]; b3s[1] = b3[1]; }

  const int base = blockIdx.x * 128;
  for (int i = tid; i < 128; i += 512) {
    if (base + i < Btot) {
      float2 v = ((const float2*)xg)[base + i];
      cxs[i][0] = v.x; cxs[i][1] = v.y;
      sxs[i][0] = v.x; sxs[i][1] = v.y;
    } else {
      cxs[i][0] = 0.f; cxs[i][1] = 0.f; sxs[i][0] = 0.f; sxs[i][1] = 0.f;
    }
    lds_ld[i] = 0.0f;
  }
  __syncthreads();

  int nst = nsp[0];
  if (nst < 1 || nst > 100000) {
    float fv = __builtin_bit_cast(float, nsp[0]);
    nst = (int)fv;
  }
  if (nst < 1) nst = 1;
  if (nst > 1000) nst = 1000;
  const int nsteps = nst - 1;
  const float hstep = (nsteps > 0) ? 1.0f / (float)nsteps : 0.0f;

  const bf16x8* w2v  = (const bf16x8*)w2u;
  const bf16x8* btrv = (const bf16x8*)btrs;
  const int sA = wv * 16 + ln15;

  for (int step = 0; step < nsteps; ++step) {
    const float t0 = step * hstep;
    #pragma unroll 1
    for (int st = 0; st < 4; ++st) {
      const float tcur = t0 + ((st == 1 || st == 2) ? 0.5f * hstep
                                                    : (st == 3 ? hstep : 0.0f));
      const float x0 = sxs[sA][0];
      const float x1 = sxs[sA][1];

      // ---- layer 1 ONCE per stage: A-frags for all 8 kt (64 VGPRs) ----
      bf16x8 hfA[8], tfA[8];
      #pragma unroll
      for (int kt = 0; kt < 8; ++kt) {
        const int kb = kt * 32 + g * 8 + (kt * 4 + g);   // k + (k>>3) swizzle
        u32x4 hu, tu;
        #pragma unroll
        for (int pp = 0; pp < 4; ++pp) {
          float4 qa = l1c[kb + 2 * pp];
          float4 qb = l1c[kb + 2 * pp + 1];
          float za = fmaf(x0, qa.x, fmaf(x1, qa.y, fmaf(tcur, qa.z, qa.w)));
          float zb = fmaf(x0, qb.x, fmaf(x1, qb.y, fmaf(tcur, qb.z, qb.w)));
          float ha = fast_tanh(za);
          float hb = fast_tanh(zb);
          hu[pp] = pk2bf(ha, hb);
          tu[pp] = pk2bf(1.0f - ha * ha, 1.0f - hb * hb);
        }
        hfA[kt] = __builtin_bit_cast(bf16x8, hu);
        tfA[kt] = __builtin_bit_cast(bf16x8, tu);
      }

      float po0[4] = {0,0,0,0}, po1[4] = {0,0,0,0}, ptr_[4] = {0,0,0,0};

      #pragma unroll 1
      for (int qn = 0; qn < 4; ++qn) {           // N quarter: j in [qn*64, +64)
        f32x4 aP[4], aT[4];
        #pragma unroll
        for (int ni = 0; ni < 4; ++ni) { aP[ni] = (f32x4)0.0f; aT[ni] = (f32x4)0.0f; }
        #pragma unroll
        for (int kt = 0; kt < 8; ++kt) {
          #pragma unroll
          for (int ni = 0; ni < 4; ++ni) {
            const int c = kt * 16 + qn * 4 + ni;
            bf16x8 bw = w2v[c * 64 + lane];      // LDS
            bf16x8 bt = btrv[c * 64 + lane];     // global, L1/L2-resident
            aP[ni] = __builtin_amdgcn_mfma_f32_16x16x32_bf16(hfA[kt], bw, aP[ni], 0, 0, 0);
            aT[ni] = __builtin_amdgcn_mfma_f32_16x16x32_bf16(tfA[kt], bt, aT[ni], 0, 0, 0);
          }
        }
        // epilogue; C layout: col=lane&15 (j), row b (sample)
        #pragma unroll
        for (int ni = 0; ni < 4; ++ni) {
          const int j = (qn * 4 + ni) * 16 + ln15;
          const float4 e = eps[j];               // w30, w31, b2
          #pragma unroll
          for (int b = 0; b < 4; ++b) {
            float z2 = aP[ni][b] + e.z;
            float h2 = fast_tanh(z2);
            float th2 = 1.0f - h2 * h2;
            po0[b]  = fmaf(h2, e.x, po0[b]);
            po1[b]  = fmaf(h2, e.y, po1[b]);
            ptr_[b] = fmaf(th2, aT[ni][b], ptr_[b]);
          }
        }
      }

      // reduce over 16 j-lanes, RK4 state update
      #pragma unroll
      for (int b = 0; b < 4; ++b) {
        float r0 = po0[b], r1 = po1[b], r2 = ptr_[b];
        #pragma unroll
        for (int off = 8; off > 0; off >>= 1) {
          r0 += __shfl_xor(r0, off, 64);
          r1 += __shfl_xor(r1, off, 64);
          r2 += __shfl_xor(r2, off, 64);
        }
        if (ln15 == 0) {
          const int s = wv * 16 + g * 4 + b;
          const float dx0 = r0 + b3s[0];
          const float dx1 = r1 + b3s[1];
          const float trv = r2;
          float k0, k1v, kl;
          if (st == 0) { k0 = dx0; k1v = dx1; kl = trv; }
          else {
            const float w = (st == 3) ? 1.0f : 2.0f;
            k0 = ksum[s][0] + w * dx0; k1v = ksum[s][1] + w * dx1; kl = lsum[s] + w * trv;
          }
          ksum[s][0] = k0; ksum[s][1] = k1v; lsum[s] = kl;
          if (st < 3) {
            const float a = (st == 2) ? hstep : 0.5f * hstep;
            sxs[s][0] = cxs[s][0] + a * dx0;
            sxs[s][1] = cxs[s][1] + a * dx1;
          } else {
            const float c6 = hstep * (1.0f / 6.0f);
            const float nx0 = cxs[s][0] + c6 * k0;
            const float nx1 = cxs[s][1] + c6 * k1v;
            cxs[s][0] = nx0; cxs[s][1] = nx1;
            sxs[s][0] = nx0; sxs[s][1] = nx1;
            lds_ld[s] -= 0.01f * c6 * kl;        // -TRACE_SCALE * (h/6) * sum
          }
        }
      }
    }
  }
  __syncthreads();

  for (int i = tid; i < 128; i += 512) {
    const int gs = base + i;
    if (gs < Btot) {
      ((float2*)out)[gs] = make_float2(cxs[i][0], cxs[i][1]);
      out[2 * Btot + gs] = lds_ld[i];
    }
  }
}

// ---------- fallback (R5-proven 3-chain LDS-only), used only if ws too small
__launch_bounds__(512, 2)
__global__ void cnf_rk4_fb(const float* __restrict__ xg,
                           const float* __restrict__ W1,
                           const float* __restrict__ b1,
                           const float* __restrict__ W2f,
                           const float* __restrict__ b2,
                           const float* __restrict__ W3,
                           const float* __restrict__ b3,
                           const int* __restrict__ nsp,
                           float* __restrict__ out,
                           int Btot) {
  __shared__ __align__(16) unsigned short w2u[65536];
  __shared__ float4 l1c[288];
  __shared__ float4 eps[256];
  __shared__ float  b3s[2];
  __shared__ float  cxs[128][2];
  __shared__ float  sxs[128][2];
  __shared__ float  ksum[128][2];
  __shared__ float  lsum[128];
  __shared__ float  lds_ld[128];

  const int tid  = threadIdx.x;
  const int lane = tid & 63;
  const int wv   = tid >> 6;
  const int ln15 = lane & 15;
  const int g    = lane >> 4;

  for (int i = tid; i < 65536; i += 512) {
    int c = i >> 9, l = (i >> 3) & 63, bb = i & 7;
    int k = ((c >> 4) << 5) + ((l >> 4) << 3) + bb;
    int j = ((c & 15) << 4) + (l & 15);
    w2u[i] = f2bf(W2f[k * 256 + j]);
  }
  for (int i = tid; i < 256; i += 512) {
    l1c[i + (i >> 3)] = make_float4(W1[i], W1[256 + i], W1[512 + i], b1[i]);
    eps[i] = make_float4(W3[2 * i], W3[2 * i + 1], b2[i], 0.0f);
  }
  if (tid == 0) { b3s[0] = b3[0]; b3s[1] = b3[1]; }

  const int base = blockIdx.x * 128;
  for (int i = tid; i < 128; i += 512) {
    if (base + i < Btot) {
      float2 v = ((const float2*)xg)[base + i];
      cxs[i][0] = v.x; cxs[i][1] = v.y;
      sxs[i][0] = v.x; sxs[i][1] = v.y;
    } else {
      cxs[i][0] = 0.f; cxs[i][1] = 0.f; sxs[i][0] = 0.f; sxs[i][1] = 0.f;
    }
    lds_ld[i] = 0.0f;
  }
  __syncthreads();

  int nst = nsp[0];
  if (nst < 1 || nst > 100000) { float fv = __builtin_bit_cast(float, nsp[0]); nst = (int)fv; }
  if (nst < 1) nst = 1;
  if (nst > 1000) nst = 1000;
  const int nsteps = nst - 1;
  const float hstep = (nsteps > 0) ? 1.0f / (float)nsteps : 0.0f;

  const bf16x8* w2v = (const bf16x8*)w2u;
  const int sA = wv * 16 + ln15;

  for (int step = 0; step < nsteps; ++step) {
    const float t0 = step * hstep;
    #pragma unroll 1
    for (int st = 0; st < 4; ++st) {
      const float tcur = t0 + ((st == 1 || st == 2) ? 0.5f * hstep
                                                    : (st == 3 ? hstep : 0.0f));
      const float x0 = sxs[sA][0];
      const float x1 = sxs[sA][1];
      float po0[4] = {0,0,0,0}, po1[4] = {0,0,0,0}, ptr_[4] = {0,0,0,0};

      #pragma unroll 1
      for (int qn = 0; qn < 4; ++qn) {
        f32x4 aP[4], aU0[4], aU1[4];
        #pragma unroll
        for (int ni = 0; ni < 4; ++ni) {
          aP[ni] = (f32x4)0.0f; aU0[ni] = (f32x4)0.0f; aU1[ni] = (f32x4)0.0f;
        }
        #pragma unroll
        for (int kt = 0; kt < 8; ++kt) {
          const int kb = kt * 32 + g * 8 + (kt * 4 + g);
          u32x4 hu, u0u, u1u;
          #pragma unroll
          for (int pp = 0; pp < 4; ++pp) {
            float4 qa = l1c[kb + 2 * pp];
            float4 qb = l1c[kb + 2 * pp + 1];
            float za = fmaf(x0, qa.x, fmaf(x1, qa.y, fmaf(tcur, qa.z, qa.w)));
            float zb = fmaf(x0, qb.x, fmaf(x1, qb.y, fmaf(tcur, qb.z, qb.w)));
            float ha = fast_tanh(za);
            float hb = fast_tanh(zb);
            float ta = 1.0f - ha * ha;
            float tb = 1.0f - hb * hb;
            hu[pp]  = pk2bf(ha, hb);
            u0u[pp] = pk2bf(ta * qa.x, tb * qb.x);
            u1u[pp] = pk2bf(ta * qa.y, tb * qb.y);
          }
          bf16x8 hf  = __builtin_bit_cast(bf16x8, hu);
          bf16x8 u0f = __builtin_bit_cast(bf16x8, u0u);
          bf16x8 u1f = __builtin_bit_cast(bf16x8, u1u);
          #pragma unroll
          for (int ni = 0; ni < 4; ++ni) {
            bf16x8 bw = w2v[(kt * 16 + qn * 4 + ni) * 64 + lane];
            aP[ni]  = __builtin_amdgcn_mfma_f32_16x16x32_bf16(hf,  bw, aP[ni],  0, 0, 0);
            aU0[ni] = __builtin_amdgcn_mfma_f32_16x16x32_bf16(u0f, bw, aU0[ni], 0, 0, 0);
            aU1[ni] = __builtin_amdgcn_mfma_f32_16x16x32_bf16(u1f, bw, aU1[ni], 0, 0, 0);
          }
        }
        #pragma unroll
        for (int ni = 0; ni < 4; ++ni) {
          const int j = (qn * 4 + ni) * 16 + ln15;
          const float4 e = eps[j];
          #pragma unroll
          for (int b = 0; b < 4; ++b) {
            float z2 = aP[ni][b] + e.z;
            float h2 = fast_tanh(z2);
            float th2 = 1.0f - h2 * h2;
            po0[b]  = fmaf(h2, e.x, po0[b]);
            po1[b]  = fmaf(h2, e.y, po1[b]);
            ptr_[b] = fmaf(th2, fmaf(aU0[ni][b], e.x, aU1[ni][b] * e.y), ptr_[b]);
          }
        }
      }
      #pragma unroll
      for (int b = 0; b < 4; ++b) {
        float r0 = po0[b], r1 = po1[b], r2 = ptr_[b];
        #pragma unroll
        for (int off = 8; off > 0; off >>= 1) {
          r0 += __shfl_xor(r0, off, 64);
          r1 += __shfl_xor(r1, off, 64);
          r2 += __shfl_xor(r2, off, 64);
        }
        if (ln15 == 0) {
          const int s = wv * 16 + g * 4 + b;
          const float dx0 = r0 + b3s[0];
          const float dx1 = r1 + b3s[1];
          const float trv = r2;
          float k0, k1v, kl;
          if (st == 0) { k0 = dx0; k1v = dx1; kl = trv; }
          else {
            const float w = (st == 3) ? 1.0f : 2.0f;
            k0 = ksum[s][0] + w * dx0; k1v = ksum[s][1] + w * dx1; kl = lsum[s] + w * trv;
          }
          ksum[s][0] = k0; ksum[s][1] = k1v; lsum[s] = kl;
          if (st < 3) {
            const float a = (st == 2) ? hstep : 0.5f * hstep;
            sxs[s][0] = cxs[s][0] + a * dx0;
            sxs[s][1] = cxs[s][1] + a * dx1;
          } else {
            const float c6 = hstep * (1.0f / 6.0f);
            const float nx0 = cxs[s][0] + c6 * k0;
            const float nx1 = cxs[s][1] + c6 * k1v;
            cxs[s][0] = nx0; cxs[s][1] = nx1;
            sxs[s][0] = nx0; sxs[s][1] = nx1;
            lds_ld[s] -= 0.01f * c6 * kl;
          }
        }
      }
    }
  }
  __syncthreads();

  for (int i = tid; i < 128; i += 512) {
    const int gs = base + i;
    if (gs < Btot) {
      ((float2*)out)[gs] = make_float2(cxs[i][0], cxs[i][1]);
      out[2 * Btot + gs] = lds_ld[i];
    }
  }
}

extern "C" void kernel_launch(void* const* d_in, const int* in_sizes, int n_in,
                              void* d_out, int out_size, void* d_ws, size_t ws_size,
                              hipStream_t stream) {
  const float* x  = (const float*)d_in[0];
  const float* W1 = (const float*)d_in[1];
  const float* b1 = (const float*)d_in[2];
  const float* W2 = (const float*)d_in[3];
  const float* b2 = (const float*)d_in[4];
  const float* W3 = (const float*)d_in[5];
  const float* b3 = (const float*)d_in[6];
  const int* nsp  = (const int*)d_in[7];
  float* out = (float*)d_out;

  const int Btot = in_sizes[0] / 2;
  const int nblocks = (Btot + 127) / 128;

  if (ws_size >= 2u * 65536u * sizeof(unsigned short)) {
    unsigned short* w2s  = (unsigned short*)d_ws;
    unsigned short* btrs = w2s + 65536;
    cnf_prep<<<dim3(32), dim3(256), 0, stream>>>(W1, W2, W3, w2s, btrs);
    cnf_rk4_v6<<<dim3(nblocks), dim3(512), 0, stream>>>(
        x, W1, b1, b2, W3, b3, w2s, btrs, nsp, out, Btot);
  } else {
    cnf_rk4_fb<<<dim3(nblocks), dim3(512), 0, stream>>>(
        x, W1, b1, W2, b2, W3, b3, nsp, out, Btot);
  }
}

// Round 7
// 4251.142 us; speedup vs baseline: 3.7238x; 1.1374x over previous
//
#include <hip/hip_runtime.h>

// CNF fused RK4, 2-chain bf16 MFMA (primal hxW2 from LDS, trace th x Btr from
// global/L2). R7: 1024-thread blocks (16 waves, 256 samples) -> 4 waves/SIMD
// for latency hiding; __launch_bounds__(1024,4) caps regs at 128/wave.

typedef __attribute__((ext_vector_type(8))) short bf16x8;
typedef __attribute__((ext_vector_type(8))) unsigned short u16x8;
typedef __attribute__((ext_vector_type(4))) float f32x4;
typedef __attribute__((ext_vector_type(4))) unsigned u32x4;

__device__ __forceinline__ unsigned short f2bf(float f) {
  unsigned u = __builtin_bit_cast(unsigned, f);
  u += 0x7FFFu + ((u >> 16) & 1u);   // RNE
  return (unsigned short)(u >> 16);
}

__device__ __forceinline__ unsigned pk2bf(float lo, float hi) {
  unsigned r;
  asm("v_cvt_pk_bf16_f32 %0, %1, %2" : "=v"(r) : "v"(lo), "v"(hi));
  return r;
}

__device__ __forceinline__ float fast_tanh(float z) {
  float e;
  float zs = z * 2.8853900817779268f;    // 2*log2(e)
  asm("v_exp_f32 %0, %1" : "=v"(e) : "v"(zs));   // e = exp(2z)
  return 1.0f - 2.0f * __builtin_amdgcn_rcpf(e + 1.0f);
}

// ---------- prep: swizzled bf16 W2 and Btr B-fragment tables ----------
// chunk c holds B[k=(c>>4)*32+(l>>4)*8+bb][j=(c&15)*16+(l&15)] at c*512+l*8+bb
__global__ void cnf_prep(const float* __restrict__ W1,
                         const float* __restrict__ W2,
                         const float* __restrict__ W3,
                         unsigned short* __restrict__ w2s,
                         unsigned short* __restrict__ btrs) {
  int t = blockIdx.x * blockDim.x + threadIdx.x;   // 8192 threads
  if (t >= 8192) return;
  int c = t >> 6, l = t & 63;
  int kbase = ((c >> 4) << 5) + ((l >> 4) << 3);
  int j = ((c & 15) << 4) + (l & 15);
  float w30 = W3[2 * j], w31 = W3[2 * j + 1];
  int o = t * 8;
  #pragma unroll
  for (int bb = 0; bb < 8; ++bb) {
    int k = kbase + bb;
    float w2 = W2[k * 256 + j];
    w2s[o + bb] = f2bf(w2);
    btrs[o + bb] = f2bf(w2 * (W1[k] * w30 + W1[256 + k] * w31));
  }
}

// ---------- main fused RK4 kernel (2-chain, hoisted L1, 16 waves) ----------
__launch_bounds__(1024, 4)
__global__ void cnf_rk4_v7(const float* __restrict__ xg,
                           const float* __restrict__ W1,
                           const float* __restrict__ b1,
                           const float* __restrict__ b2,
                           const float* __restrict__ W3,
                           const float* __restrict__ b3,
                           const unsigned short* __restrict__ w2s,
                           const unsigned short* __restrict__ btrs,
                           const int* __restrict__ nsp,
                           float* __restrict__ out,
                           int Btot) {
  __shared__ __align__(16) unsigned short w2u[65536];  // 128 KB, B-frag layout
  __shared__ float4 l1c[288];   // (W1_0,W1_1,W1_2,b1) at k + (k>>3) (injective)
  __shared__ float4 eps[256];   // (W3_0, W3_1, b2, 0)
  __shared__ float  b3s[2];
  __shared__ float  cxs[256][2];
  __shared__ float  sxs[256][2];
  __shared__ float  ksum[256][2];
  __shared__ float  lsum[256];
  __shared__ float  lds_ld[256];

  const int tid  = threadIdx.x;
  const int lane = tid & 63;
  const int wv   = tid >> 6;       // wave 0..15
  const int ln15 = lane & 15;
  const int g    = lane >> 4;

  {  // stage pre-swizzled W2 into LDS (vector copy, L2/L3-hot)
    u16x8* dst = (u16x8*)w2u;
    const u16x8* src = (const u16x8*)w2s;
    for (int i = tid; i < 8192; i += 1024) dst[i] = src[i];
  }
  for (int i = tid; i < 256; i += 1024) {
    l1c[i + (i >> 3)] = make_float4(W1[i], W1[256 + i], W1[512 + i], b1[i]);
    eps[i] = make_float4(W3[2 * i], W3[2 * i + 1], b2[i], 0.0f);
  }
  if (tid == 0) { b3s[0] = b3[0]; b3s[1] = b3[1]; }

  const int base = blockIdx.x * 256;
  for (int i = tid; i < 256; i += 1024) {
    if (base + i < Btot) {
      float2 v = ((const float2*)xg)[base + i];
      cxs[i][0] = v.x; cxs[i][1] = v.y;
      sxs[i][0] = v.x; sxs[i][1] = v.y;
    } else {
      cxs[i][0] = 0.f; cxs[i][1] = 0.f; sxs[i][0] = 0.f; sxs[i][1] = 0.f;
    }
    lds_ld[i] = 0.0f;
  }
  __syncthreads();

  int nst = nsp[0];
  if (nst < 1 || nst > 100000) {
    float fv = __builtin_bit_cast(float, nsp[0]);
    nst = (int)fv;
  }
  if (nst < 1) nst = 1;
  if (nst > 1000) nst = 1000;
  const int nsteps = nst - 1;
  const float hstep = (nsteps > 0) ? 1.0f / (float)nsteps : 0.0f;

  const bf16x8* w2v  = (const bf16x8*)w2u;
  const bf16x8* btrv = (const bf16x8*)btrs;
  const int sA = wv * 16 + ln15;

  for (int step = 0; step < nsteps; ++step) {
    const float t0 = step * hstep;
    #pragma unroll 1
    for (int st = 0; st < 4; ++st) {
      const float tcur = t0 + ((st == 1 || st == 2) ? 0.5f * hstep
                                                    : (st == 3 ? hstep : 0.0f));
      const float x0 = sxs[sA][0];
      const float x1 = sxs[sA][1];

      // ---- layer 1 ONCE per stage: A-frags for all 8 kt (64 VGPRs) ----
      bf16x8 hfA[8], tfA[8];
      #pragma unroll
      for (int kt = 0; kt < 8; ++kt) {
        const int kb = kt * 32 + g * 8 + (kt * 4 + g);   // k + (k>>3) swizzle
        u32x4 hu, tu;
        #pragma unroll
        for (int pp = 0; pp < 4; ++pp) {
          float4 qa = l1c[kb + 2 * pp];
          float4 qb = l1c[kb + 2 * pp + 1];
          float za = fmaf(x0, qa.x, fmaf(x1, qa.y, fmaf(tcur, qa.z, qa.w)));
          float zb = fmaf(x0, qb.x, fmaf(x1, qb.y, fmaf(tcur, qb.z, qb.w)));
          float ha = fast_tanh(za);
          float hb = fast_tanh(zb);
          hu[pp] = pk2bf(ha, hb);
          tu[pp] = pk2bf(1.0f - ha * ha, 1.0f - hb * hb);
        }
        hfA[kt] = __builtin_bit_cast(bf16x8, hu);
        tfA[kt] = __builtin_bit_cast(bf16x8, tu);
      }

      float po0[4] = {0,0,0,0}, po1[4] = {0,0,0,0}, ptr_[4] = {0,0,0,0};

      #pragma unroll 1
      for (int qn = 0; qn < 4; ++qn) {           // N quarter: j in [qn*64, +64)
        f32x4 aP[4], aT[4];
        #pragma unroll
        for (int ni = 0; ni < 4; ++ni) { aP[ni] = (f32x4)0.0f; aT[ni] = (f32x4)0.0f; }
        #pragma unroll
        for (int kt = 0; kt < 8; ++kt) {
          #pragma unroll
          for (int ni = 0; ni < 4; ++ni) {
            const int c = kt * 16 + qn * 4 + ni;
            bf16x8 bw = w2v[c * 64 + lane];      // LDS
            bf16x8 bt = btrv[c * 64 + lane];     // global, L1/L2-resident
            aP[ni] = __builtin_amdgcn_mfma_f32_16x16x32_bf16(hfA[kt], bw, aP[ni], 0, 0, 0);
            aT[ni] = __builtin_amdgcn_mfma_f32_16x16x32_bf16(tfA[kt], bt, aT[ni], 0, 0, 0);
          }
        }
        // epilogue; C layout: col=lane&15 (j), row b (sample)
        #pragma unroll
        for (int ni = 0; ni < 4; ++ni) {
          const int j = (qn * 4 + ni) * 16 + ln15;
          const float4 e = eps[j];               // w30, w31, b2
          #pragma unroll
          for (int b = 0; b < 4; ++b) {
            float z2 = aP[ni][b] + e.z;
            float h2 = fast_tanh(z2);
            float th2 = 1.0f - h2 * h2;
            po0[b]  = fmaf(h2, e.x, po0[b]);
            po1[b]  = fmaf(h2, e.y, po1[b]);
            ptr_[b] = fmaf(th2, aT[ni][b], ptr_[b]);
          }
        }
      }

      // reduce over 16 j-lanes, RK4 state update
      #pragma unroll
      for (int b = 0; b < 4; ++b) {
        float r0 = po0[b], r1 = po1[b], r2 = ptr_[b];
        #pragma unroll
        for (int off = 8; off > 0; off >>= 1) {
          r0 += __shfl_xor(r0, off, 64);
          r1 += __shfl_xor(r1, off, 64);
          r2 += __shfl_xor(r2, off, 64);
        }
        if (ln15 == 0) {
          const int s = wv * 16 + g * 4 + b;
          const float dx0 = r0 + b3s[0];
          const float dx1 = r1 + b3s[1];
          const float trv = r2;
          float k0, k1v, kl;
          if (st == 0) { k0 = dx0; k1v = dx1; kl = trv; }
          else {
            const float w = (st == 3) ? 1.0f : 2.0f;
            k0 = ksum[s][0] + w * dx0; k1v = ksum[s][1] + w * dx1; kl = lsum[s] + w * trv;
          }
          ksum[s][0] = k0; ksum[s][1] = k1v; lsum[s] = kl;
          if (st < 3) {
            const float a = (st == 2) ? hstep : 0.5f * hstep;
            sxs[s][0] = cxs[s][0] + a * dx0;
            sxs[s][1] = cxs[s][1] + a * dx1;
          } else {
            const float c6 = hstep * (1.0f / 6.0f);
            const float nx0 = cxs[s][0] + c6 * k0;
            const float nx1 = cxs[s][1] + c6 * k1v;
            cxs[s][0] = nx0; cxs[s][1] = nx1;
            sxs[s][0] = nx0; sxs[s][1] = nx1;
            lds_ld[s] -= 0.01f * c6 * kl;        // -TRACE_SCALE * (h/6) * sum
          }
        }
      }
    }
  }
  __syncthreads();

  for (int i = tid; i < 256; i += 1024) {
    const int gs = base + i;
    if (gs < Btot) {
      ((float2*)out)[gs] = make_float2(cxs[i][0], cxs[i][1]);
      out[2 * Btot + gs] = lds_ld[i];
    }
  }
}

// ---------- fallback (R6-proven, 512 threads, used only if ws too small) ----
__launch_bounds__(512, 2)
__global__ void cnf_rk4_fb(const float* __restrict__ xg,
                           const float* __restrict__ W1,
                           const float* __restrict__ b1,
                           const float* __restrict__ W2f,
                           const float* __restrict__ b2,
                           const float* __restrict__ W3,
                           const float* __restrict__ b3,
                           const int* __restrict__ nsp,
                           float* __restrict__ out,
                           int Btot) {
  __shared__ __align__(16) unsigned short w2u[65536];
  __shared__ float4 l1c[288];
  __shared__ float4 eps[256];
  __shared__ float  b3s[2];
  __shared__ float  cxs[128][2];
  __shared__ float  sxs[128][2];
  __shared__ float  ksum[128][2];
  __shared__ float  lsum[128];
  __shared__ float  lds_ld[128];

  const int tid  = threadIdx.x;
  const int lane = tid & 63;
  const int wv   = tid >> 6;
  const int ln15 = lane & 15;
  const int g    = lane >> 4;

  for (int i = tid; i < 65536; i += 512) {
    int c = i >> 9, l = (i >> 3) & 63, bb = i & 7;
    int k = ((c >> 4) << 5) + ((l >> 4) << 3) + bb;
    int j = ((c & 15) << 4) + (l & 15);
    w2u[i] = f2bf(W2f[k * 256 + j]);
  }
  for (int i = tid; i < 256; i += 512) {
    l1c[i + (i >> 3)] = make_float4(W1[i], W1[256 + i], W1[512 + i], b1[i]);
    eps[i] = make_float4(W3[2 * i], W3[2 * i + 1], b2[i], 0.0f);
  }
  if (tid == 0) { b3s[0] = b3[0]; b3s[1] = b3[1]; }

  const int base = blockIdx.x * 128;
  for (int i = tid; i < 128; i += 512) {
    if (base + i < Btot) {
      float2 v = ((const float2*)xg)[base + i];
      cxs[i][0] = v.x; cxs[i][1] = v.y;
      sxs[i][0] = v.x; sxs[i][1] = v.y;
    } else {
      cxs[i][0] = 0.f; cxs[i][1] = 0.f; sxs[i][0] = 0.f; sxs[i][1] = 0.f;
    }
    lds_ld[i] = 0.0f;
  }
  __syncthreads();

  int nst = nsp[0];
  if (nst < 1 || nst > 100000) { float fv = __builtin_bit_cast(float, nsp[0]); nst = (int)fv; }
  if (nst < 1) nst = 1;
  if (nst > 1000) nst = 1000;
  const int nsteps = nst - 1;
  const float hstep = (nsteps > 0) ? 1.0f / (float)nsteps : 0.0f;

  const bf16x8* w2v = (const bf16x8*)w2u;
  const int sA = wv * 16 + ln15;

  for (int step = 0; step < nsteps; ++step) {
    const float t0 = step * hstep;
    #pragma unroll 1
    for (int st = 0; st < 4; ++st) {
      const float tcur = t0 + ((st == 1 || st == 2) ? 0.5f * hstep
                                                    : (st == 3 ? hstep : 0.0f));
      const float x0 = sxs[sA][0];
      const float x1 = sxs[sA][1];
      float po0[4] = {0,0,0,0}, po1[4] = {0,0,0,0}, ptr_[4] = {0,0,0,0};

      #pragma unroll 1
      for (int qn = 0; qn < 4; ++qn) {
        f32x4 aP[4], aU0[4], aU1[4];
        #pragma unroll
        for (int ni = 0; ni < 4; ++ni) {
          aP[ni] = (f32x4)0.0f; aU0[ni] = (f32x4)0.0f; aU1[ni] = (f32x4)0.0f;
        }
        #pragma unroll
        for (int kt = 0; kt < 8; ++kt) {
          const int kb = kt * 32 + g * 8 + (kt * 4 + g);
          u32x4 hu, u0u, u1u;
          #pragma unroll
          for (int pp = 0; pp < 4; ++pp) {
            float4 qa = l1c[kb + 2 * pp];
            float4 qb = l1c[kb + 2 * pp + 1];
            float za = fmaf(x0, qa.x, fmaf(x1, qa.y, fmaf(tcur, qa.z, qa.w)));
            float zb = fmaf(x0, qb.x, fmaf(x1, qb.y, fmaf(tcur, qb.z, qb.w)));
            float ha = fast_tanh(za);
            float hb = fast_tanh(zb);
            float ta = 1.0f - ha * ha;
            float tb = 1.0f - hb * hb;
            hu[pp]  = pk2bf(ha, hb);
            u0u[pp] = pk2bf(ta * qa.x, tb * qb.x);
            u1u[pp] = pk2bf(ta * qa.y, tb * qb.y);
          }
          bf16x8 hf  = __builtin_bit_cast(bf16x8, hu);
          bf16x8 u0f = __builtin_bit_cast(bf16x8, u0u);
          bf16x8 u1f = __builtin_bit_cast(bf16x8, u1u);
          #pragma unroll
          for (int ni = 0; ni < 4; ++ni) {
            bf16x8 bw = w2v[(kt * 16 + qn * 4 + ni) * 64 + lane];
            aP[ni]  = __builtin_amdgcn_mfma_f32_16x16x32_bf16(hf,  bw, aP[ni],  0, 0, 0);
            aU0[ni] = __builtin_amdgcn_mfma_f32_16x16x32_bf16(u0f, bw, aU0[ni], 0, 0, 0);
            aU1[ni] = __builtin_amdgcn_mfma_f32_16x16x32_bf16(u1f, bw, aU1[ni], 0, 0, 0);
          }
        }
        #pragma unroll
        for (int ni = 0; ni < 4; ++ni) {
          const int j = (qn * 4 + ni) * 16 + ln15;
          const float4 e = eps[j];
          #pragma unroll
          for (int b = 0; b < 4; ++b) {
            float z2 = aP[ni][b] + e.z;
            float h2 = fast_tanh(z2);
            float th2 = 1.0f - h2 * h2;
            po0[b]  = fmaf(h2, e.x, po0[b]);
            po1[b]  = fmaf(h2, e.y, po1[b]);
            ptr_[b] = fmaf(th2, fmaf(aU0[ni][b], e.x, aU1[ni][b] * e.y), ptr_[b]);
          }
        }
      }
      #pragma unroll
      for (int b = 0; b < 4; ++b) {
        float r0 = po0[b], r1 = po1[b], r2 = ptr_[b];
        #pragma unroll
        for (int off = 8; off > 0; off >>= 1) {
          r0 += __shfl_xor(r0, off, 64);
          r1 += __shfl_xor(r1, off, 64);
          r2 += __shfl_xor(r2, off, 64);
        }
        if (ln15 == 0) {
          const int s = wv * 16 + g * 4 + b;
          const float dx0 = r0 + b3s[0];
          const float dx1 = r1 + b3s[1];
          const float trv = r2;
          float k0, k1v, kl;
          if (st == 0) { k0 = dx0; k1v = dx1; kl = trv; }
          else {
            const float w = (st == 3) ? 1.0f : 2.0f;
            k0 = ksum[s][0] + w * dx0; k1v = ksum[s][1] + w * dx1; kl = lsum[s] + w * trv;
          }
          ksum[s][0] = k0; ksum[s][1] = k1v; lsum[s] = kl;
          if (st < 3) {
            const float a = (st == 2) ? hstep : 0.5f * hstep;
            sxs[s][0] = cxs[s][0] + a * dx0;
            sxs[s][1] = cxs[s][1] + a * dx1;
          } else {
            const float c6 = hstep * (1.0f / 6.0f);
            const float nx0 = cxs[s][0] + c6 * k0;
            const float nx1 = cxs[s][1] + c6 * k1v;
            cxs[s][0] = nx0; cxs[s][1] = nx1;
            sxs[s][0] = nx0; sxs[s][1] = nx1;
            lds_ld[s] -= 0.01f * c6 * kl;
          }
        }
      }
    }
  }
  __syncthreads();

  for (int i = tid; i < 128; i += 512) {
    const int gs = base + i;
    if (gs < Btot) {
      ((float2*)out)[gs] = make_float2(cxs[i][0], cxs[i][1]);
      out[2 * Btot + gs] = lds_ld[i];
    }
  }
}

extern "C" void kernel_launch(void* const* d_in, const int* in_sizes, int n_in,
                              void* d_out, int out_size, void* d_ws, size_t ws_size,
                              hipStream_t stream) {
  const float* x  = (const float*)d_in[0];
  const float* W1 = (const float*)d_in[1];
  const float* b1 = (const float*)d_in[2];
  const float* W2 = (const float*)d_in[3];
  const float* b2 = (const float*)d_in[4];
  const float* W3 = (const float*)d_in[5];
  const float* b3 = (const float*)d_in[6];
  const int* nsp  = (const int*)d_in[7];
  float* out = (float*)d_out;

  const int Btot = in_sizes[0] / 2;

  if (ws_size >= 2u * 65536u * sizeof(unsigned short)) {
    unsigned short* w2s  = (unsigned short*)d_ws;
    unsigned short* btrs = w2s + 65536;
    cnf_prep<<<dim3(32), dim3(256), 0, stream>>>(W1, W2, W3, w2s, btrs);
    const int nblocks = (Btot + 255) / 256;
    cnf_rk4_v7<<<dim3(nblocks), dim3(1024), 0, stream>>>(
        x, W1, b1, b2, W3, b3, w2s, btrs, nsp, out, Btot);
  } else {
    const int nblocks = (Btot + 127) / 128;
    cnf_rk4_fb<<<dim3(nblocks), dim3(512), 0, stream>>>(
        x, W1, b1, W2, b2, W3, b3, nsp, out, Btot);
  }
}

// Round 8
// 3982.210 us; speedup vs baseline: 3.9752x; 1.0675x over previous
//
#include <hip/hip_runtime.h>

// CNF fused RK4, 3-chain bf16 MFMA (primal + 2 JVP tangents), ALL B-operands
// from the single W2 LDS table (128 KB) -- no global B stream (R7 showed the
// Btr global stream was L2-BW-bound at ~25 B/cyc/CU).
// 768 threads = 12 waves = 3 waves/SIMD -> 170-reg budget: hoisted A-frags
// (96) + N-eighth accumulators (24) + partials fit without spilling.

typedef __attribute__((ext_vector_type(8))) short bf16x8;
typedef __attribute__((ext_vector_type(8))) unsigned short u16x8;
typedef __attribute__((ext_vector_type(4))) float f32x4;
typedef __attribute__((ext_vector_type(4))) unsigned u32x4;

__device__ __forceinline__ unsigned short f2bf(float f) {
  unsigned u = __builtin_bit_cast(unsigned, f);
  u += 0x7FFFu + ((u >> 16) & 1u);   // RNE
  return (unsigned short)(u >> 16);
}

__device__ __forceinline__ unsigned pk2bf(float lo, float hi) {
  unsigned r;
  asm("v_cvt_pk_bf16_f32 %0, %1, %2" : "=v"(r) : "v"(lo), "v"(hi));
  return r;
}

__device__ __forceinline__ float fast_tanh(float z) {
  float e;
  float zs = z * 2.8853900817779268f;    // 2*log2(e)
  asm("v_exp_f32 %0, %1" : "=v"(e) : "v"(zs));   // e = exp(2z)
  return 1.0f - 2.0f * __builtin_amdgcn_rcpf(e + 1.0f);
}

// ---------- prep: swizzle W2 -> bf16 B-fragment layout in d_ws ----------
// chunk c holds B[k=(c>>4)*32+(l>>4)*8+bb][j=(c&15)*16+(l&15)] at c*512+l*8+bb
__global__ void cnf_prep(const float* __restrict__ W2,
                         unsigned short* __restrict__ w2s) {
  int t = blockIdx.x * blockDim.x + threadIdx.x;   // 8192 threads
  if (t >= 8192) return;
  int c = t >> 6, l = t & 63;
  int kbase = ((c >> 4) << 5) + ((l >> 4) << 3);
  int j = ((c & 15) << 4) + (l & 15);
  int o = t * 8;
  #pragma unroll
  for (int bb = 0; bb < 8; ++bb)
    w2s[o + bb] = f2bf(W2[(kbase + bb) * 256 + j]);
}

// ---------- main fused RK4 kernel ----------
__launch_bounds__(768, 3)
__global__ void cnf_rk4_v8(const float* __restrict__ xg,
                           const float* __restrict__ W1,
                           const float* __restrict__ b1,
                           const float* __restrict__ W2f,
                           const float* __restrict__ b2,
                           const float* __restrict__ W3,
                           const float* __restrict__ b3,
                           const unsigned short* __restrict__ w2s,
                           const int* __restrict__ nsp,
                           float* __restrict__ out,
                           int Btot, int useWs) {
  __shared__ __align__(16) unsigned short w2u[65536];  // 128 KB, B-frag layout
  __shared__ float4 l1c[288];   // (W1_0,W1_1,W1_2,b1) at k + (k>>3) (injective)
  __shared__ float4 eps[256];   // (W3_0, W3_1, b2, 0)
  __shared__ float  b3s[2];
  __shared__ float  cxs[192][2];
  __shared__ float  sxs[192][2];
  __shared__ float  ksum[192][2];
  __shared__ float  lsum[192];
  __shared__ float  lds_ld[192];

  const int tid  = threadIdx.x;
  const int lane = tid & 63;
  const int wv   = tid >> 6;       // wave 0..11
  const int ln15 = lane & 15;
  const int g    = lane >> 4;

  if (useWs) {            // fast staging: vector copy of pre-swizzled bf16
    u16x8* dst = (u16x8*)w2u;
    const u16x8* src = (const u16x8*)w2s;
    for (int i = tid; i < 8192; i += 768) dst[i] = src[i];
  } else {                // fallback: convert in-kernel
    for (int i = tid; i < 65536; i += 768) {
      int c = i >> 9, l = (i >> 3) & 63, bb = i & 7;
      int k = ((c >> 4) << 5) + ((l >> 4) << 3) + bb;
      int j = ((c & 15) << 4) + (l & 15);
      w2u[i] = f2bf(W2f[k * 256 + j]);
    }
  }
  for (int i = tid; i < 256; i += 768) {
    l1c[i + (i >> 3)] = make_float4(W1[i], W1[256 + i], W1[512 + i], b1[i]);
    eps[i] = make_float4(W3[2 * i], W3[2 * i + 1], b2[i], 0.0f);
  }
  if (tid == 0) { b3s[0] = b3[0]; b3s[1] = b3[1]; }

  const int base = blockIdx.x * 192;
  for (int i = tid; i < 192; i += 768) {
    if (base + i < Btot) {
      float2 v = ((const float2*)xg)[base + i];
      cxs[i][0] = v.x; cxs[i][1] = v.y;
      sxs[i][0] = v.x; sxs[i][1] = v.y;
    } else {
      cxs[i][0] = 0.f; cxs[i][1] = 0.f; sxs[i][0] = 0.f; sxs[i][1] = 0.f;
    }
    lds_ld[i] = 0.0f;
  }
  __syncthreads();

  int nst = nsp[0];
  if (nst < 1 || nst > 100000) {
    float fv = __builtin_bit_cast(float, nsp[0]);
    nst = (int)fv;
  }
  if (nst < 1) nst = 1;
  if (nst > 1000) nst = 1000;
  const int nsteps = nst - 1;
  const float hstep = (nsteps > 0) ? 1.0f / (float)nsteps : 0.0f;

  const bf16x8* w2v = (const bf16x8*)w2u;
  const int sA = wv * 16 + ln15;

  for (int step = 0; step < nsteps; ++step) {
    const float t0 = step * hstep;
    #pragma unroll 1
    for (int st = 0; st < 4; ++st) {
      const float tcur = t0 + ((st == 1 || st == 2) ? 0.5f * hstep
                                                    : (st == 3 ? hstep : 0.0f));
      const float x0 = sxs[sA][0];
      const float x1 = sxs[sA][1];

      // ---- layer 1 ONCE per stage: A-frags for all 8 kt, 3 chains (96 regs)
      bf16x8 hfA[8], u0A[8], u1A[8];
      #pragma unroll
      for (int kt = 0; kt < 8; ++kt) {
        const int kb = kt * 32 + g * 8 + (kt * 4 + g);   // k + (k>>3) swizzle
        u32x4 hu, u0u, u1u;
        #pragma unroll
        for (int pp = 0; pp < 4; ++pp) {
          float4 qa = l1c[kb + 2 * pp];
          float4 qb = l1c[kb + 2 * pp + 1];
          float za = fmaf(x0, qa.x, fmaf(x1, qa.y, fmaf(tcur, qa.z, qa.w)));
          float zb = fmaf(x0, qb.x, fmaf(x1, qb.y, fmaf(tcur, qb.z, qb.w)));
          float ha = fast_tanh(za);
          float hb = fast_tanh(zb);
          float ta = 1.0f - ha * ha;
          float tb = 1.0f - hb * hb;
          hu[pp]  = pk2bf(ha, hb);
          u0u[pp] = pk2bf(ta * qa.x, tb * qb.x);   // (1-h^2)*W1[0,k]
          u1u[pp] = pk2bf(ta * qa.y, tb * qb.y);   // (1-h^2)*W1[1,k]
        }
        hfA[kt] = __builtin_bit_cast(bf16x8, hu);
        u0A[kt] = __builtin_bit_cast(bf16x8, u0u);
        u1A[kt] = __builtin_bit_cast(bf16x8, u1u);
      }

      float po0[4] = {0,0,0,0}, po1[4] = {0,0,0,0}, ptr_[4] = {0,0,0,0};

      #pragma unroll 1
      for (int ph = 0; ph < 8; ++ph) {           // N eighth: j in [ph*32, +32)
        f32x4 aP[2], aU0[2], aU1[2];
        #pragma unroll
        for (int ni = 0; ni < 2; ++ni) {
          aP[ni] = (f32x4)0.0f; aU0[ni] = (f32x4)0.0f; aU1[ni] = (f32x4)0.0f;
        }
        #pragma unroll
        for (int kt = 0; kt < 8; ++kt) {
          #pragma unroll
          for (int ni = 0; ni < 2; ++ni) {
            const int c = kt * 16 + ph * 2 + ni;
            bf16x8 bw = w2v[c * 64 + lane];      // 1 LDS read feeds 3 MFMAs
            aP[ni]  = __builtin_amdgcn_mfma_f32_16x16x32_bf16(hfA[kt], bw, aP[ni],  0, 0, 0);
            aU0[ni] = __builtin_amdgcn_mfma_f32_16x16x32_bf16(u0A[kt], bw, aU0[ni], 0, 0, 0);
            aU1[ni] = __builtin_amdgcn_mfma_f32_16x16x32_bf16(u1A[kt], bw, aU1[ni], 0, 0, 0);
          }
        }
        // epilogue; C layout: col=lane&15 (j), row b (sample)
        #pragma unroll
        for (int ni = 0; ni < 2; ++ni) {
          const int j = (ph * 2 + ni) * 16 + ln15;
          const float4 e = eps[j];               // w30, w31, b2
          #pragma unroll
          for (int b = 0; b < 4; ++b) {
            float z2 = aP[ni][b] + e.z;
            float h2 = fast_tanh(z2);
            float th2 = 1.0f - h2 * h2;
            po0[b]  = fmaf(h2, e.x, po0[b]);
            po1[b]  = fmaf(h2, e.y, po1[b]);
            ptr_[b] = fmaf(th2, fmaf(aU0[ni][b], e.x, aU1[ni][b] * e.y), ptr_[b]);
          }
        }
      }

      // reduce over 16 j-lanes, RK4 state update
      #pragma unroll
      for (int b = 0; b < 4; ++b) {
        float r0 = po0[b], r1 = po1[b], r2 = ptr_[b];
        #pragma unroll
        for (int off = 8; off > 0; off >>= 1) {
          r0 += __shfl_xor(r0, off, 64);
          r1 += __shfl_xor(r1, off, 64);
          r2 += __shfl_xor(r2, off, 64);
        }
        if (ln15 == 0) {
          const int s = wv * 16 + g * 4 + b;
          const float dx0 = r0 + b3s[0];
          const float dx1 = r1 + b3s[1];
          const float trv = r2;
          float k0, k1v, kl;
          if (st == 0) { k0 = dx0; k1v = dx1; kl = trv; }
          else {
            const float w = (st == 3) ? 1.0f : 2.0f;
            k0 = ksum[s][0] + w * dx0; k1v = ksum[s][1] + w * dx1; kl = lsum[s] + w * trv;
          }
          ksum[s][0] = k0; ksum[s][1] = k1v; lsum[s] = kl;
          if (st < 3) {
            const float a = (st == 2) ? hstep : 0.5f * hstep;
            sxs[s][0] = cxs[s][0] + a * dx0;
            sxs[s][1] = cxs[s][1] + a * dx1;
          } else {
            const float c6 = hstep * (1.0f / 6.0f);
            const float nx0 = cxs[s][0] + c6 * k0;
            const float nx1 = cxs[s][1] + c6 * k1v;
            cxs[s][0] = nx0; cxs[s][1] = nx1;
            sxs[s][0] = nx0; sxs[s][1] = nx1;
            lds_ld[s] -= 0.01f * c6 * kl;        // -TRACE_SCALE * (h/6) * sum
          }
        }
      }
    }
  }
  __syncthreads();

  for (int i = tid; i < 192; i += 768) {
    const int gs = base + i;
    if (gs < Btot) {
      ((float2*)out)[gs] = make_float2(cxs[i][0], cxs[i][1]);
      out[2 * Btot + gs] = lds_ld[i];
    }
  }
}

extern "C" void kernel_launch(void* const* d_in, const int* in_sizes, int n_in,
                              void* d_out, int out_size, void* d_ws, size_t ws_size,
                              hipStream_t stream) {
  const float* x  = (const float*)d_in[0];
  const float* W1 = (const float*)d_in[1];
  const float* b1 = (const float*)d_in[2];
  const float* W2 = (const float*)d_in[3];
  const float* b2 = (const float*)d_in[4];
  const float* W3 = (const float*)d_in[5];
  const float* b3 = (const float*)d_in[6];
  const int* nsp  = (const int*)d_in[7];
  float* out = (float*)d_out;

  const int Btot = in_sizes[0] / 2;
  const int nblocks = (Btot + 191) / 192;

  const int useWs = (ws_size >= 65536u * sizeof(unsigned short)) ? 1 : 0;
  unsigned short* w2s = (unsigned short*)d_ws;
  if (useWs)
    cnf_prep<<<dim3(32), dim3(256), 0, stream>>>(W2, w2s);
  cnf_rk4_v8<<<dim3(nblocks), dim3(768), 0, stream>>>(
      x, W1, b1, W2, b2, W3, b3, w2s, nsp, out, Btot, useWs);
}

// Round 9
// 3877.209 us; speedup vs baseline: 4.0829x; 1.0271x over previous
//
#include <hip/hip_runtime.h>

// CNF fused RK4, 3-chain bf16 MFMA (primal + 2 JVP tangents), ALL B-operands
// from the single W2 LDS table (128 KB). 768 thr = 12 waves = 3 waves/SIMD.
// R9: exp-scale constant c = 2*log2(e) folded into l1c/W2/b2 tables (kills
// one mul per tanh); trace rescaled by 1/c^2 at the RK4 update. s_setprio(1)
// around the MFMA cluster (barrier-free waves at different phases -> T5).

typedef __attribute__((ext_vector_type(8))) short bf16x8;
typedef __attribute__((ext_vector_type(8))) unsigned short u16x8;
typedef __attribute__((ext_vector_type(4))) float f32x4;
typedef __attribute__((ext_vector_type(4))) unsigned u32x4;

#define CSC 2.8853900817779268f      /* 2*log2(e) */
#define INV_C2 0.12011325347010204f  /* 1/CSC^2 */

__device__ __forceinline__ unsigned short f2bf(float f) {
  unsigned u = __builtin_bit_cast(unsigned, f);
  u += 0x7FFFu + ((u >> 16) & 1u);   // RNE
  return (unsigned short)(u >> 16);
}

__device__ __forceinline__ unsigned pk2bf(float lo, float hi) {
  unsigned r;
  asm("v_cvt_pk_bf16_f32 %0, %1, %2" : "=v"(r) : "v"(lo), "v"(hi));
  return r;
}

// tanh from PRE-SCALED argument zs = 2*log2(e)*z : tanh(z) = 1 - 2/(2^zs + 1)
__device__ __forceinline__ float tanh_s(float zs) {
  float e;
  asm("v_exp_f32 %0, %1" : "=v"(e) : "v"(zs));
  return 1.0f - 2.0f * __builtin_amdgcn_rcpf(e + 1.0f);
}

// ---------- prep: swizzle c*W2 -> bf16 B-fragment layout in d_ws ----------
// chunk c holds B[k=(c>>4)*32+(l>>4)*8+bb][j=(c&15)*16+(l&15)] at c*512+l*8+bb
__global__ void cnf_prep(const float* __restrict__ W2,
                         unsigned short* __restrict__ w2s) {
  int t = blockIdx.x * blockDim.x + threadIdx.x;   // 8192 threads
  if (t >= 8192) return;
  int c = t >> 6, l = t & 63;
  int kbase = ((c >> 4) << 5) + ((l >> 4) << 3);
  int j = ((c & 15) << 4) + (l & 15);
  int o = t * 8;
  #pragma unroll
  for (int bb = 0; bb < 8; ++bb)
    w2s[o + bb] = f2bf(CSC * W2[(kbase + bb) * 256 + j]);
}

// ---------- main fused RK4 kernel ----------
__launch_bounds__(768, 3)
__global__ void cnf_rk4_v9(const float* __restrict__ xg,
                           const float* __restrict__ W1,
                           const float* __restrict__ b1,
                           const float* __restrict__ W2f,
                           const float* __restrict__ b2,
                           const float* __restrict__ W3,
                           const float* __restrict__ b3,
                           const unsigned short* __restrict__ w2s,
                           const int* __restrict__ nsp,
                           float* __restrict__ out,
                           int Btot, int useWs) {
  __shared__ __align__(16) unsigned short w2u[65536];  // 128 KB, c*W2 B-frags
  __shared__ float4 l1c[288];   // c*(W1_0,W1_1,W1_2,b1) at k + (k>>3)
  __shared__ float4 eps[256];   // (W3_0, W3_1, c*b2, 0)
  __shared__ float  b3s[2];
  __shared__ float  cxs[192][2];
  __shared__ float  sxs[192][2];
  __shared__ float  ksum[192][2];
  __shared__ float  lsum[192];
  __shared__ float  lds_ld[192];

  const int tid  = threadIdx.x;
  const int lane = tid & 63;
  const int wv   = tid >> 6;       // wave 0..11
  const int ln15 = lane & 15;
  const int g    = lane >> 4;

  if (useWs) {            // fast staging: vector copy of pre-swizzled bf16
    u16x8* dst = (u16x8*)w2u;
    const u16x8* src = (const u16x8*)w2s;
    for (int i = tid; i < 8192; i += 768) dst[i] = src[i];
  } else {                // fallback: convert in-kernel
    for (int i = tid; i < 65536; i += 768) {
      int c = i >> 9, l = (i >> 3) & 63, bb = i & 7;
      int k = ((c >> 4) << 5) + ((l >> 4) << 3) + bb;
      int j = ((c & 15) << 4) + (l & 15);
      w2u[i] = f2bf(CSC * W2f[k * 256 + j]);
    }
  }
  for (int i = tid; i < 256; i += 768) {
    l1c[i + (i >> 3)] = make_float4(CSC * W1[i], CSC * W1[256 + i],
                                    CSC * W1[512 + i], CSC * b1[i]);
    eps[i] = make_float4(W3[2 * i], W3[2 * i + 1], CSC * b2[i], 0.0f);
  }
  if (tid == 0) { b3s[0] = b3[0]; b3s[1] = b3[1]; }

  const int base = blockIdx.x * 192;
  for (int i = tid; i < 192; i += 768) {
    if (base + i < Btot) {
      float2 v = ((const float2*)xg)[base + i];
      cxs[i][0] = v.x; cxs[i][1] = v.y;
      sxs[i][0] = v.x; sxs[i][1] = v.y;
    } else {
      cxs[i][0] = 0.f; cxs[i][1] = 0.f; sxs[i][0] = 0.f; sxs[i][1] = 0.f;
    }
    lds_ld[i] = 0.0f;
  }
  __syncthreads();

  int nst = nsp[0];
  if (nst < 1 || nst > 100000) {
    float fv = __builtin_bit_cast(float, nsp[0]);
    nst = (int)fv;
  }
  if (nst < 1) nst = 1;
  if (nst > 1000) nst = 1000;
  const int nsteps = nst - 1;
  const float hstep = (nsteps > 0) ? 1.0f / (float)nsteps : 0.0f;

  const bf16x8* w2v = (const bf16x8*)w2u;
  const int sA = wv * 16 + ln15;

  for (int step = 0; step < nsteps; ++step) {
    const float t0 = step * hstep;
    #pragma unroll 1
    for (int st = 0; st < 4; ++st) {
      const float tcur = t0 + ((st == 1 || st == 2) ? 0.5f * hstep
                                                    : (st == 3 ? hstep : 0.0f));
      const float x0 = sxs[sA][0];
      const float x1 = sxs[sA][1];

      // ---- layer 1 ONCE per stage: A-frags for all 8 kt, 3 chains ----
      // l1c is c-scaled: the z chain directly yields the exp argument.
      bf16x8 hfA[8], u0A[8], u1A[8];
      #pragma unroll
      for (int kt = 0; kt < 8; ++kt) {
        const int kb = kt * 32 + g * 8 + (kt * 4 + g);   // k + (k>>3) swizzle
        u32x4 hu, u0u, u1u;
        #pragma unroll
        for (int pp = 0; pp < 4; ++pp) {
          float4 qa = l1c[kb + 2 * pp];
          float4 qb = l1c[kb + 2 * pp + 1];
          float za = fmaf(x0, qa.x, fmaf(x1, qa.y, fmaf(tcur, qa.z, qa.w)));
          float zb = fmaf(x0, qb.x, fmaf(x1, qb.y, fmaf(tcur, qb.z, qb.w)));
          float ha = tanh_s(za);
          float hb = tanh_s(zb);
          float ta = 1.0f - ha * ha;
          float tb = 1.0f - hb * hb;
          hu[pp]  = pk2bf(ha, hb);
          u0u[pp] = pk2bf(ta * qa.x, tb * qb.x);   // th * (c*W1[0,k])
          u1u[pp] = pk2bf(ta * qa.y, tb * qb.y);   // th * (c*W1[1,k])
        }
        hfA[kt] = __builtin_bit_cast(bf16x8, hu);
        u0A[kt] = __builtin_bit_cast(bf16x8, u0u);
        u1A[kt] = __builtin_bit_cast(bf16x8, u1u);
      }

      float po0[4] = {0,0,0,0}, po1[4] = {0,0,0,0}, ptr_[4] = {0,0,0,0};

      #pragma unroll 1
      for (int ph = 0; ph < 8; ++ph) {           // N eighth: j in [ph*32, +32)
        f32x4 aP[2], aU0[2], aU1[2];
        #pragma unroll
        for (int ni = 0; ni < 2; ++ni) {
          aP[ni] = (f32x4)0.0f; aU0[ni] = (f32x4)0.0f; aU1[ni] = (f32x4)0.0f;
        }
        __builtin_amdgcn_s_setprio(1);           // favor MFMA-phase waves
        #pragma unroll
        for (int kt = 0; kt < 8; ++kt) {
          #pragma unroll
          for (int ni = 0; ni < 2; ++ni) {
            const int c = kt * 16 + ph * 2 + ni;
            bf16x8 bw = w2v[c * 64 + lane];      // 1 LDS read feeds 3 MFMAs
            aP[ni]  = __builtin_amdgcn_mfma_f32_16x16x32_bf16(hfA[kt], bw, aP[ni],  0, 0, 0);
            aU0[ni] = __builtin_amdgcn_mfma_f32_16x16x32_bf16(u0A[kt], bw, aU0[ni], 0, 0, 0);
            aU1[ni] = __builtin_amdgcn_mfma_f32_16x16x32_bf16(u1A[kt], bw, aU1[ni], 0, 0, 0);
          }
        }
        __builtin_amdgcn_s_setprio(0);
        // epilogue; C layout: col=lane&15 (j), row b (sample).
        // aP is c-scaled (c*W2): aP + c*b2 is the exp argument directly.
        #pragma unroll
        for (int ni = 0; ni < 2; ++ni) {
          const int j = (ph * 2 + ni) * 16 + ln15;
          const float4 e = eps[j];               // w30, w31, c*b2
          #pragma unroll
          for (int b = 0; b < 4; ++b) {
            float h2 = tanh_s(aP[ni][b] + e.z);
            float th2 = 1.0f - h2 * h2;
            po0[b]  = fmaf(h2, e.x, po0[b]);
            po1[b]  = fmaf(h2, e.y, po1[b]);
            ptr_[b] = fmaf(th2, fmaf(aU0[ni][b], e.x, aU1[ni][b] * e.y), ptr_[b]);
          }
        }
      }

      // reduce over 16 j-lanes, RK4 state update
      #pragma unroll
      for (int b = 0; b < 4; ++b) {
        float r0 = po0[b], r1 = po1[b], r2 = ptr_[b];
        #pragma unroll
        for (int off = 8; off > 0; off >>= 1) {
          r0 += __shfl_xor(r0, off, 64);
          r1 += __shfl_xor(r1, off, 64);
          r2 += __shfl_xor(r2, off, 64);
        }
        if (ln15 == 0) {
          const int s = wv * 16 + g * 4 + b;
          const float dx0 = r0 + b3s[0];
          const float dx1 = r1 + b3s[1];
          const float trv = r2 * INV_C2;         // undo c^2 from u-chain & W2
          float k0, k1v, kl;
          if (st == 0) { k0 = dx0; k1v = dx1; kl = trv; }
          else {
            const float w = (st == 3) ? 1.0f : 2.0f;
            k0 = ksum[s][0] + w * dx0; k1v = ksum[s][1] + w * dx1; kl = lsum[s] + w * trv;
          }
          ksum[s][0] = k0; ksum[s][1] = k1v; lsum[s] = kl;
          if (st < 3) {
            const float a = (st == 2) ? hstep : 0.5f * hstep;
            sxs[s][0] = cxs[s][0] + a * dx0;
            sxs[s][1] = cxs[s][1] + a * dx1;
          } else {
            const float c6 = hstep * (1.0f / 6.0f);
            const float nx0 = cxs[s][0] + c6 * k0;
            const float nx1 = cxs[s][1] + c6 * k1v;
            cxs[s][0] = nx0; cxs[s][1] = nx1;
            sxs[s][0] = nx0; sxs[s][1] = nx1;
            lds_ld[s] -= 0.01f * c6 * kl;        // -TRACE_SCALE * (h/6) * sum
          }
        }
      }
    }
  }
  __syncthreads();

  for (int i = tid; i < 192; i += 768) {
    const int gs = base + i;
    if (gs < Btot) {
      ((float2*)out)[gs] = make_float2(cxs[i][0], cxs[i][1]);
      out[2 * Btot + gs] = lds_ld[i];
    }
  }
}

extern "C" void kernel_launch(void* const* d_in, const int* in_sizes, int n_in,
                              void* d_out, int out_size, void* d_ws, size_t ws_size,
                              hipStream_t stream) {
  const float* x  = (const float*)d_in[0];
  const float* W1 = (const float*)d_in[1];
  const float* b1 = (const float*)d_in[2];
  const float* W2 = (const float*)d_in[3];
  const float* b2 = (const float*)d_in[4];
  const float* W3 = (const float*)d_in[5];
  const float* b3 = (const float*)d_in[6];
  const int* nsp  = (const int*)d_in[7];
  float* out = (float*)d_out;

  const int Btot = in_sizes[0] / 2;
  const int nblocks = (Btot + 191) / 192;

  const int useWs = (ws_size >= 65536u * sizeof(unsigned short)) ? 1 : 0;
  unsigned short* w2s = (unsigned short*)d_ws;
  if (useWs)
    cnf_prep<<<dim3(32), dim3(256), 0, stream>>>(W2, w2s);
  cnf_rk4_v9<<<dim3(nblocks), dim3(768), 0, stream>>>(
      x, W1, b1, W2, b2, W3, b3, w2s, nsp, out, Btot, useWs);
}